// Round 7
// baseline (236.740 us; speedup 1.0000x reference)
//
#include <hip/hip_runtime.h>
#include <hip/hip_fp16.h>
#include <math.h>

#define IN_F 64
#define OUT_F 32
#define NEG_SLOPE 0.2f

#define NBMAX 512        // max coarse buckets (N <= 131072 with >>8)
#define NBLKA 256        // edge-pass block count (also the per-bucket scan width)

__device__ __forceinline__ float leaky(float v) {
    return (v > 0.0f) ? v : NEG_SLOPE * v;
}

// h = x @ W  (N x 64 @ 64 x 32) stored as two split fp16 tables (ch 0-15, 16-31),
// plus a_src/a_dst logits. 8 nodes/block, 32 lanes per node (lane = channel).
__global__ void k_proj(const float* __restrict__ x, const float* __restrict__ W,
                       const float* __restrict__ att_src, const float* __restrict__ att_dst,
                       __half2* __restrict__ hlo, __half2* __restrict__ hhi,
                       float* __restrict__ asrc, float* __restrict__ adst, int N) {
    __shared__ float Ws[IN_F * OUT_F];
    __shared__ float xs[8 * IN_F];
    const int tid = threadIdx.x;
    for (int i = tid; i < IN_F * OUT_F; i += 256) Ws[i] = W[i];
    const int base = blockIdx.x * 8;
    for (int i = tid; i < 8 * IN_F; i += 256) {
        int node = base + i / IN_F;
        xs[i] = (node < N) ? x[(size_t)base * IN_F + i] : 0.0f;
    }
    __syncthreads();

    const int ln = tid >> 5;
    const int c  = tid & 31;
    const int node = base + ln;
    float sum = 0.0f;
    #pragma unroll
    for (int k = 0; k < IN_F; ++k) sum += xs[ln * IN_F + k] * Ws[k * OUT_F + c];

    float s1 = __shfl_xor(sum, 1);          // partner channel's value
    if (node < N) {
        if ((c & 1) == 0) {
            __half2 hv;
            hv.x = __float2half_rn(sum);
            hv.y = __float2half_rn(s1);
            int p = c >> 1;                  // half2 index 0..15
            if (p < 8) hlo[(size_t)node * 8 + p] = hv;
            else       hhi[(size_t)node * 8 + (p - 8)] = hv;
        }
        float vs = sum * att_src[c];
        float vd = sum * att_dst[c];
        #pragma unroll
        for (int m = 16; m >= 1; m >>= 1) {
            vs += __shfl_xor(vs, m);
            vd += __shfl_xor(vd, m);
        }
        if (c == 0) {
            asrc[node] = vs;
            adst[node] = vd;
        }
    }
}

// Pass A: per-block coarse histogram (bucket = d>>8) into hist[bucket][block].
__global__ void k_bhist(const int* __restrict__ dst, int* __restrict__ hist,
                        int NB, int E, int epb) {
    __shared__ int lh[NBMAX];
    const int tid = threadIdx.x, blk = blockIdx.x;   // 512 threads
    for (int i = tid; i < NB; i += 512) lh[i] = 0;
    __syncthreads();
    const int e0 = blk * epb, e1 = min(E, e0 + epb);
    for (int e = e0 + tid; e < e1; e += 512) atomicAdd(&lh[dst[e] >> 8], 1);
    __syncthreads();
    for (int b = tid; b < NB; b += 512) hist[(size_t)b * NBLKA + blk] = lh[b];
}

// Scan 1: per-256-block exclusive scan (in place) + block sums.
// Bucket-major layout: each scan block covers exactly one coarse bucket, so
// bsum[b] (after k_scan2) is the bucket's global base offset.
__global__ void k_scan1(int* __restrict__ data, int* __restrict__ bsum, int M) {
    const int tid = threadIdx.x;
    const int i = blockIdx.x * 256 + tid;
    int v = (i < M) ? data[i] : 0;
    const int orig = v;
    const int lane = tid & 63;
    #pragma unroll
    for (int m = 1; m < 64; m <<= 1) {
        int u = __shfl_up(v, m);
        if (lane >= m) v += u;
    }
    __shared__ int wt[4];
    if (lane == 63) wt[tid >> 6] = v;
    __syncthreads();
    if (tid < 64) {
        int w = (tid < 4) ? wt[tid] : 0;
        #pragma unroll
        for (int m = 1; m < 4; m <<= 1) {
            int u = __shfl_up(w, m);
            if (tid >= m) w += u;
        }
        if (tid < 4) wt[tid] = w;
    }
    __syncthreads();
    if (tid >= 64) v += wt[(tid >> 6) - 1];
    if (i < M) data[i] = v - orig;
    if (tid == 255) bsum[blockIdx.x] = v;
}

// Scan 2: single-block exclusive scan of bucket totals (nb <= 512).
__global__ void k_scan2(int* __restrict__ bsum, int nb) {
    const int tid = threadIdx.x;            // 512
    int v = (tid < nb) ? bsum[tid] : 0;
    const int orig = v;
    const int lane = tid & 63;
    #pragma unroll
    for (int m = 1; m < 64; m <<= 1) {
        int u = __shfl_up(v, m);
        if (lane >= m) v += u;
    }
    __shared__ int wt[8];
    if (lane == 63) wt[tid >> 6] = v;
    __syncthreads();
    if (tid < 64) {
        int w = (tid < 8) ? wt[tid] : 0;
        #pragma unroll
        for (int m = 1; m < 8; m <<= 1) {
            int u = __shfl_up(w, m);
            if (tid >= m) w += u;
        }
        if (tid < 8) wt[tid] = w;
    }
    __syncthreads();
    if (tid >= 64) v += wt[(tid >> 6) - 1];
    if (tid < nb) bsum[tid] = v - orig;
}

// Pass B: place packed records (d&255)<<17 | s into block-private runs.
__global__ void k_bpart(const int* __restrict__ src, const int* __restrict__ dst,
                        const int* __restrict__ histScan, const int* __restrict__ bsum,
                        int* __restrict__ recs, int NB, int E, int epb) {
    __shared__ int lcur[NBMAX];
    const int tid = threadIdx.x, blk = blockIdx.x;   // 512 threads
    for (int b = tid; b < NB; b += 512)
        lcur[b] = histScan[(size_t)b * NBLKA + blk] + bsum[b];
    __syncthreads();
    const int e0 = blk * epb, e1 = min(E, e0 + epb);
    for (int e = e0 + tid; e < e1; e += 512) {
        int s = src[e];
        int d = dst[e];
        int p = atomicAdd(&lcur[d >> 8], 1);   // LDS atomic, block-private
        recs[p] = ((d & 255) << 17) | s;
    }
}

// Pass C: one block per coarse bucket. Fine 256-node histogram + scan in LDS,
// emit cnt/offs (coalesced), place col into a contiguous window.
__global__ void k_place(const int* __restrict__ recs, const int* __restrict__ bsum,
                        int* __restrict__ cnt, int* __restrict__ offs,
                        int* __restrict__ col, int NB, int E, int N) {
    __shared__ int fineCnt[256];
    __shared__ int cur[256];
    __shared__ int wsum[4];
    const int b = blockIdx.x, tid = threadIdx.x;
    const int cb0 = bsum[b];
    const int cb1 = (b + 1 < NB) ? bsum[b + 1] : E;
    const int count = cb1 - cb0;
    fineCnt[tid] = 0;
    __syncthreads();
    for (int i = tid; i < count; i += 256)
        atomicAdd(&fineCnt[recs[cb0 + i] >> 17], 1);
    __syncthreads();
    const int v0 = fineCnt[tid];
    const int lane = tid & 63, wid = tid >> 6;
    int v = v0;
    #pragma unroll
    for (int m = 1; m < 64; m <<= 1) {
        int u = __shfl_up(v, m);
        if (lane >= m) v += u;
    }
    if (lane == 63) wsum[wid] = v;
    __syncthreads();
    int add = 0;
    for (int k = 0; k < wid; ++k) add += wsum[k];
    v += add;
    const int excl = v - v0;
    const int node = (b << 8) + tid;
    if (node < N) {
        cnt[node]  = v0;
        offs[node] = cb0 + excl;
    }
    cur[tid] = cb0 + excl;
    __syncthreads();
    for (int i = tid; i < count; i += 256) {
        int r = recs[cb0 + i];
        int p = atomicAdd(&cur[r >> 17], 1);
        col[p] = r & 0x1FFFF;
    }
}

// Channel-split gather: 16 channels per pass; h table (N x 32 B) fits per-XCD L2.
// One wave per node: 8 edge groups x 8 lanes (half2 channel pair) -> 8 chains,
// 32 B coalesced row per edge. Softmax denominator recomputed redundantly per
// pass (1 exp/edge, VALU-cheap; asrc L2-hot). Groups merged via shfl_xor.
__global__ void k_gather16(const int* __restrict__ col, const int* __restrict__ offs,
                           const int* __restrict__ cnt, const float* __restrict__ asrc,
                           const float* __restrict__ adst, const __half2* __restrict__ h2,
                           const float* __restrict__ bias16, float* __restrict__ out,
                           int N, int cofs) {
    int t = blockIdx.x * 256 + threadIdx.x;
    int n = t >> 6;
    if (n >= N) return;
    const int lane = t & 63;
    const int g  = lane >> 3;    // edge group 0..7
    const int c2 = lane & 7;     // half2 channel pair 0..7
    const float adst_n = adst[n];
    float l = 0.0f, accx = 0.0f, accy = 0.0f;
    if (g == 0) {                // self loop
        float p = __expf(leaky(asrc[n] + adst_n));
        float2 hv = __half22float2(h2[(size_t)n * 8 + c2]);
        l = p;
        accx = p * hv.x;
        accy = p * hv.y;
    }
    const int off = offs[n];
    const int deg = cnt[n];
    for (int i = g; i < deg; i += 8) {
        int s = col[off + i];
        float p = __expf(leaky(asrc[s] + adst_n));
        float2 hv = __half22float2(h2[(size_t)s * 8 + c2]);
        l += p;
        accx += p * hv.x;
        accy += p * hv.y;
    }
    l    += __shfl_xor(l, 8);    l    += __shfl_xor(l, 16);    l    += __shfl_xor(l, 32);
    accx += __shfl_xor(accx, 8); accx += __shfl_xor(accx, 16); accx += __shfl_xor(accx, 32);
    accy += __shfl_xor(accy, 8); accy += __shfl_xor(accy, 16); accy += __shfl_xor(accy, 32);
    if (g == 0) {
        float inv = 1.0f / l;
        float2 bb = ((const float2*)bias16)[c2];
        float2 o;
        o.x = fmaxf(accx * inv + bb.x, 0.0f);
        o.y = fmaxf(accy * inv + bb.y, 0.0f);
        ((float2*)(out + (size_t)n * OUT_F + cofs))[c2] = o;  // 8 lanes x 8 B = 64 B line
    }
}

extern "C" void kernel_launch(void* const* d_in, const int* in_sizes, int n_in,
                              void* d_out, int out_size, void* d_ws, size_t ws_size,
                              hipStream_t stream) {
    const float* x        = (const float*)d_in[0];
    const int*   eidx     = (const int*)d_in[1];   // [2, E] flat int32
    const float* W        = (const float*)d_in[2];
    const float* att_src  = (const float*)d_in[3];
    const float* att_dst  = (const float*)d_in[4];
    const float* bias     = (const float*)d_in[5];
    float* out = (float*)d_out;

    const int N = in_sizes[0] / IN_F;
    const int E = in_sizes[1] / 2;
    const int* src = eidx;
    const int* dst = eidx + E;

    const int NB  = (N + 255) >> 8;          // 391 coarse buckets
    const int M   = NB * NBLKA;              // hist domain (~100K)
    const int epb = (E + NBLKA - 1) / NBLKA; // edges per pass-A/B block

    // Workspace (4 B elems, ~15 MB). recs aliases the split h tables: recs dies
    // in k_place, which runs before k_proj writes hlo/hhi. Region = max(E, N*16) ints.
    int* u = (int*)d_ws;
    const size_t hregion = ((size_t)E > (size_t)N * 16) ? (size_t)E : (size_t)N * 16;
    __half2* hlo     = (__half2*)u;              // N*8 half2 (ch 0-15)
    __half2* hhi     = hlo + (size_t)N * 8;      // N*8 half2 (ch 16-31)
    int*     recs    = u;                        // E (alias)
    float*   asrc    = (float*)(u + hregion);    // N
    float*   adst    = asrc + N;                 // N
    int*     cnt     = (int*)(adst + N);         // N
    int*     offs    = cnt + N;                  // N
    int*     hist    = offs + N;                 // M (scanned in place)
    int*     bsum    = hist + M;                 // 512
    int*     col     = bsum + 512;               // E

    const int scanBlocks   = (M + 255) / 256;              // = NB <= 512
    const int nodeBlocks8  = (N + 7) / 8;
    const int gatherBlocks = ((size_t)N * 64 + 255) / 256; // one wave per node

    k_bhist<<<NBLKA, 512, 0, stream>>>(dst, hist, NB, E, epb);
    k_scan1<<<scanBlocks, 256, 0, stream>>>(hist, bsum, M);
    k_scan2<<<1, 512, 0, stream>>>(bsum, scanBlocks);
    k_bpart<<<NBLKA, 512, 0, stream>>>(src, dst, hist, bsum, recs, NB, E, epb);
    k_place<<<NB, 256, 0, stream>>>(recs, bsum, cnt, offs, col, NB, E, N);
    k_proj<<<nodeBlocks8, 256, 0, stream>>>(x, W, att_src, att_dst, hlo, hhi, asrc, adst, N);
    k_gather16<<<gatherBlocks, 256, 0, stream>>>(col, offs, cnt, asrc, adst, hlo, bias, out, N, 0);
    k_gather16<<<gatherBlocks, 256, 0, stream>>>(col, offs, cnt, asrc, adst, hhi, bias + 16, out, N, 16);
}

// Round 9
// 197.202 us; speedup vs baseline: 1.2005x; 1.2005x over previous
//
#include <hip/hip_runtime.h>
#include <hip/hip_fp16.h>
#include <math.h>

#define IN_F 64
#define OUT_F 32
#define NEG_SLOPE 0.2f

#define NBMAX 512        // max coarse buckets (N <= 131072 with >>8)
#define NBLKA 256        // edge-pass block count (= per-bucket scan width)
#define PSTAGE 20        // k_place register-stage depth (count <= 256*20 always)

__device__ __forceinline__ float leaky(float v) {
    return (v > 0.0f) ? v : NEG_SLOPE * v;
}

// Fused: blocks [0, PB) do the projection GEMM; blocks [PB, PB+NBLKA) do the
// coarse histogram. Independent inputs -> one launch, overlapped execution.
__global__ __launch_bounds__(256) void k_projhist(
        const float* __restrict__ x, const float* __restrict__ W,
        const float* __restrict__ att_src, const float* __restrict__ att_dst,
        __half2* __restrict__ h2, float* __restrict__ asrc, float* __restrict__ adst,
        const int* __restrict__ dst, int* __restrict__ hist,
        int N, int NB, int E, int epb, int PB) {
    __shared__ int smem[2560];               // 10 KB, overlaid per role
    const int tid = threadIdx.x;

    if (blockIdx.x >= PB) {
        // ---- coarse histogram role ----
        int* lh = smem;
        const int blk = blockIdx.x - PB;
        for (int i = tid; i < NB; i += 256) lh[i] = 0;
        __syncthreads();
        const int e0 = blk * epb, e1 = min(E, e0 + epb);
        for (int e = e0 + tid; e < e1; e += 256) atomicAdd(&lh[dst[e] >> 8], 1);
        __syncthreads();
        for (int b = tid; b < NB; b += 256) hist[(size_t)b * NBLKA + blk] = lh[b];
        return;
    }

    // ---- projection role: h = x @ W (8 nodes/block), logits ----
    float* Ws = (float*)smem;                // 2048 floats
    float* xs = Ws + IN_F * OUT_F;           // 512 floats
    for (int i = tid; i < IN_F * OUT_F; i += 256) Ws[i] = W[i];
    const int base = blockIdx.x * 8;
    for (int i = tid; i < 8 * IN_F; i += 256) {
        int node = base + i / IN_F;
        xs[i] = (node < N) ? x[(size_t)base * IN_F + i] : 0.0f;
    }
    __syncthreads();

    const int ln = tid >> 5;
    const int c  = tid & 31;
    const int node = base + ln;
    float sum = 0.0f;
    #pragma unroll
    for (int k = 0; k < IN_F; ++k) sum += xs[ln * IN_F + k] * Ws[k * OUT_F + c];

    float s1 = __shfl_xor(sum, 1);
    if (node < N) {
        if ((c & 1) == 0) {
            __half2 hv;
            hv.x = __float2half_rn(sum);
            hv.y = __float2half_rn(s1);
            h2[(size_t)node * 16 + (c >> 1)] = hv;
        }
        float vs = sum * att_src[c];
        float vd = sum * att_dst[c];
        #pragma unroll
        for (int m = 16; m >= 1; m >>= 1) {
            vs += __shfl_xor(vs, m);
            vd += __shfl_xor(vd, m);
        }
        if (c == 0) {
            asrc[node] = vs;
            adst[node] = vd;
        }
    }
}

// Scan 1: per-256-block exclusive scan (in place) + block (=bucket) sums.
__global__ void k_scan1(int* __restrict__ data, int* __restrict__ bsum, int M) {
    const int tid = threadIdx.x;
    const int i = blockIdx.x * 256 + tid;
    int v = (i < M) ? data[i] : 0;
    const int orig = v;
    const int lane = tid & 63;
    #pragma unroll
    for (int m = 1; m < 64; m <<= 1) {
        int u = __shfl_up(v, m);
        if (lane >= m) v += u;
    }
    __shared__ int wt[4];
    if (lane == 63) wt[tid >> 6] = v;
    __syncthreads();
    if (tid < 64) {
        int w = (tid < 4) ? wt[tid] : 0;
        #pragma unroll
        for (int m = 1; m < 4; m <<= 1) {
            int u = __shfl_up(w, m);
            if (tid >= m) w += u;
        }
        if (tid < 4) wt[tid] = w;
    }
    __syncthreads();
    if (tid >= 64) v += wt[(tid >> 6) - 1];
    if (i < M) data[i] = v - orig;
    if (tid == 255) bsum[blockIdx.x] = v;
}

// Scan 2: single-block exclusive scan of bucket totals (nb <= 512).
__global__ void k_scan2(int* __restrict__ bsum, int nb) {
    const int tid = threadIdx.x;            // 512
    int v = (tid < nb) ? bsum[tid] : 0;
    const int orig = v;
    const int lane = tid & 63;
    #pragma unroll
    for (int m = 1; m < 64; m <<= 1) {
        int u = __shfl_up(v, m);
        if (lane >= m) v += u;
    }
    __shared__ int wt[8];
    if (lane == 63) wt[tid >> 6] = v;
    __syncthreads();
    if (tid < 64) {
        int w = (tid < 8) ? wt[tid] : 0;
        #pragma unroll
        for (int m = 1; m < 8; m <<= 1) {
            int u = __shfl_up(w, m);
            if (tid >= m) w += u;
        }
        if (tid < 8) wt[tid] = w;
    }
    __syncthreads();
    if (tid >= 64) v += wt[(tid >> 6) - 1];
    if (tid < nb) bsum[tid] = v - orig;
}

// Pass B: place packed records (d&255)<<17 | s into block-private runs.
__global__ void k_bpart(const int* __restrict__ src, const int* __restrict__ dst,
                        const int* __restrict__ histScan, const int* __restrict__ bsum,
                        int* __restrict__ recs, int NB, int E, int epb) {
    __shared__ int lcur[NBMAX];
    const int tid = threadIdx.x, blk = blockIdx.x;   // 512 threads
    for (int b = tid; b < NB; b += 512)
        lcur[b] = histScan[(size_t)b * NBLKA + blk] + bsum[b];
    __syncthreads();
    const int e0 = blk * epb, e1 = min(E, e0 + epb);
    for (int e = e0 + tid; e < e1; e += 512) {
        int s = src[e];
        int d = dst[e];
        int p = atomicAdd(&lcur[d >> 8], 1);   // LDS atomic, block-private
        recs[p] = ((d & 255) << 17) | s;
    }
}

// Pass C: one block per coarse bucket. Records staged in registers (static
// indices -> no scratch), fine histogram + scan in LDS, cnt/offs coalesced,
// col placed into a contiguous window.
__global__ void k_place(const int* __restrict__ recs, const int* __restrict__ bsum,
                        int* __restrict__ cnt, int* __restrict__ offs,
                        int* __restrict__ col, int NB, int E, int N) {
    __shared__ int fineCnt[256];
    __shared__ int cur[256];
    __shared__ int wsum[4];
    const int b = blockIdx.x, tid = threadIdx.x;
    const int cb0 = bsum[b];
    const int cb1 = (b + 1 < NB) ? bsum[b + 1] : E;
    const int count = cb1 - cb0;
    int myrec[PSTAGE];
    fineCnt[tid] = 0;
    __syncthreads();
    #pragma unroll
    for (int k = 0; k < PSTAGE; ++k) {
        int i = tid + k * 256;
        if (i < count) {
            int v = recs[cb0 + i];
            myrec[k] = v;
            atomicAdd(&fineCnt[v >> 17], 1);
        }
    }
    for (int i = tid + PSTAGE * 256; i < count; i += 256)   // statistically never
        atomicAdd(&fineCnt[recs[cb0 + i] >> 17], 1);
    __syncthreads();
    const int v0 = fineCnt[tid];
    const int lane = tid & 63, wid = tid >> 6;
    int v = v0;
    #pragma unroll
    for (int m = 1; m < 64; m <<= 1) {
        int u = __shfl_up(v, m);
        if (lane >= m) v += u;
    }
    if (lane == 63) wsum[wid] = v;
    __syncthreads();
    int add = 0;
    for (int k = 0; k < wid; ++k) add += wsum[k];
    v += add;
    const int excl = v - v0;
    const int node = (b << 8) + tid;
    if (node < N) {
        cnt[node]  = v0;
        offs[node] = cb0 + excl;
    }
    cur[tid] = cb0 + excl;
    __syncthreads();
    #pragma unroll
    for (int k = 0; k < PSTAGE; ++k) {
        int i = tid + k * 256;
        if (i < count) {
            int r = myrec[k];
            int p = atomicAdd(&cur[r >> 17], 1);
            col[p] = r & 0x1FFFF;
        }
    }
    for (int i = tid + PSTAGE * 256; i < count; i += 256) {
        int r = recs[cb0 + i];
        int p = atomicAdd(&cur[r >> 17], 1);
        col[p] = r & 0x1FFFF;
    }
}

// Gather: one wave per node, 4 groups x 16 lanes (half2 channel pair).
// Each group takes a CONTIGUOUS quarter of the edge list and processes it in
// chunks of 4: 4 col loads -> 4 asrc + 4 h2 loads all in flight -> exps -> fma.
// Latency-bound chain depth drops ~4x vs one-edge-at-a-time.
__global__ void k_gather(const int* __restrict__ col, const int* __restrict__ offs,
                         const int* __restrict__ cnt, const float* __restrict__ asrc,
                         const float* __restrict__ adst, const __half2* __restrict__ h2,
                         const float* __restrict__ bias, float* __restrict__ out, int N) {
    int t = blockIdx.x * 256 + threadIdx.x;
    int n = t >> 6;
    if (n >= N) return;
    const int lane = t & 63;
    const int g  = lane >> 4;    // edge group 0..3
    const int c2 = lane & 15;    // half2 channel pair 0..15
    const float adst_n = adst[n];
    float l = 0.0f, accx = 0.0f, accy = 0.0f;
    if (g == 0) {                // self loop
        float p = __expf(leaky(asrc[n] + adst_n));
        float2 hv = __half22float2(h2[(size_t)n * 16 + c2]);
        l = p;
        accx = p * hv.x;
        accy = p * hv.y;
    }
    const int off = offs[n];
    const int deg = cnt[n];
    const int q = (deg + 3) >> 2;            // quarter size
    int j    = off + g * q;
    const int jend = min(j + q, off + deg);
    for (; j + 3 < jend; j += 4) {
        int s0 = col[j], s1 = col[j + 1], s2 = col[j + 2], s3 = col[j + 3];
        float a0 = asrc[s0], a1 = asrc[s1], a2 = asrc[s2], a3 = asrc[s3];
        float2 h0 = __half22float2(h2[(size_t)s0 * 16 + c2]);
        float2 h1 = __half22float2(h2[(size_t)s1 * 16 + c2]);
        float2 hv2 = __half22float2(h2[(size_t)s2 * 16 + c2]);
        float2 h3 = __half22float2(h2[(size_t)s3 * 16 + c2]);
        float p0 = __expf(leaky(a0 + adst_n));
        float p1 = __expf(leaky(a1 + adst_n));
        float p2 = __expf(leaky(a2 + adst_n));
        float p3 = __expf(leaky(a3 + adst_n));
        l += (p0 + p1) + (p2 + p3);
        accx += p0 * h0.x + p1 * h1.x + p2 * hv2.x + p3 * h3.x;
        accy += p0 * h0.y + p1 * h1.y + p2 * hv2.y + p3 * h3.y;
    }
    for (; j < jend; ++j) {
        int s = col[j];
        float p = __expf(leaky(asrc[s] + adst_n));
        float2 hv = __half22float2(h2[(size_t)s * 16 + c2]);
        l += p;
        accx += p * hv.x;
        accy += p * hv.y;
    }
    l    += __shfl_xor(l, 16);    l    += __shfl_xor(l, 32);
    accx += __shfl_xor(accx, 16); accx += __shfl_xor(accx, 32);
    accy += __shfl_xor(accy, 16); accy += __shfl_xor(accy, 32);
    if (g == 0) {
        float inv = 1.0f / l;
        float2 bb = ((const float2*)bias)[c2];
        float2 o;
        o.x = fmaxf(accx * inv + bb.x, 0.0f);
        o.y = fmaxf(accy * inv + bb.y, 0.0f);
        ((float2*)out)[(size_t)n * 16 + c2] = o;
    }
}

extern "C" void kernel_launch(void* const* d_in, const int* in_sizes, int n_in,
                              void* d_out, int out_size, void* d_ws, size_t ws_size,
                              hipStream_t stream) {
    const float* x        = (const float*)d_in[0];
    const int*   eidx     = (const int*)d_in[1];   // [2, E] flat int32
    const float* W        = (const float*)d_in[2];
    const float* att_src  = (const float*)d_in[3];
    const float* att_dst  = (const float*)d_in[4];
    const float* bias     = (const float*)d_in[5];
    float* out = (float*)d_out;

    const int N = in_sizes[0] / IN_F;
    const int E = in_sizes[1] / 2;
    const int* src = eidx;
    const int* dst = eidx + E;

    const int NB  = (N + 255) >> 8;          // 391 coarse buckets
    const int M   = NB * NBLKA;              // hist domain (~100K)
    const int epb = (E + NBLKA - 1) / NBLKA; // edges per hist/bpart block

    // Workspace (4 B elems, ~19 MB). recs gets its own slot (no h2 aliasing:
    // the fused k_projhist writes h2 FIRST, before recs dies).
    int* u = (int*)d_ws;
    __half2* h2      = (__half2*)u;              // N*16 half2
    float*   asrc    = (float*)(u + (size_t)N * 16);   // N
    float*   adst    = asrc + N;                 // N
    int*     cnt     = (int*)(adst + N);         // N
    int*     offs    = cnt + N;                  // N
    int*     hist    = offs + N;                 // M (scanned in place)
    int*     bsum    = hist + M;                 // 512
    int*     col     = bsum + 512;               // E
    int*     recs    = col + E;                  // E (own slot: proj runs first now)

    const int PB = (N + 7) / 8;                  // proj blocks in fused kernel
    const int scanBlocks   = (M + 255) / 256;    // = NB <= 512
    const int gatherBlocks = ((size_t)N * 64 + 255) / 256;

    k_projhist<<<PB + NBLKA, 256, 0, stream>>>(x, W, att_src, att_dst, h2, asrc, adst,
                                               dst, hist, N, NB, E, epb, PB);
    k_scan1<<<scanBlocks, 256, 0, stream>>>(hist, bsum, M);
    k_scan2<<<1, 512, 0, stream>>>(bsum, scanBlocks);
    k_bpart<<<NBLKA, 512, 0, stream>>>(src, dst, hist, bsum, recs, NB, E, epb);
    k_place<<<NB, 256, 0, stream>>>(recs, bsum, cnt, offs, col, NB, E, N);
    k_gather<<<gatherBlocks, 256, 0, stream>>>(col, offs, cnt, asrc, adst, h2, bias, out, N);
}